// Round 2
// baseline (224.321 us; speedup 1.0000x reference)
//
#include <hip/hip_runtime.h>
#include <cstdint>
#include <cstddef>

// Problem constants (fixed by the reference file)
#define B_SZ  8
#define C_IN  2049          // N_FFT/2+1
#define T_FR  345           // MAX_FRAMES
#define NFFT  4096
#define HOPSZ 1024
#define MFR   2760          // B_SZ*T_FR frames
#define NPAIR 173           // ceil(345/2) frame-pairs per batch
#define TW    1.5339807878856412e-3f   // 2*pi/4096
#define TW256 2.4543692606170259e-2f   // 2*pi/256
// Interior window_sum is exactly 1.5 (sum of 4 phase-shifted hann^2):
// wsi = 4096/(1.5*1024 + 1e-8)
#define W_INT 2.6666666666484f

// e^{i*pi/8} family for the in-register 16-pt IDFT
#define C8P   0.70710678118654752f
#define C16C  0.92387953251128676f
#define C16S  0.38268343236508977f

__device__ __forceinline__ unsigned short f2b(float f) {
  union { float f; unsigned int u; } v; v.f = f;
  unsigned int r = v.u + 0x7fffu + ((v.u >> 16) & 1u);  // RNE to bf16
  return (unsigned short)(r >> 16);
}
__device__ __forceinline__ float b2f(unsigned int h) {
  union { unsigned int u; float f; } v; v.u = h << 16;
  return v.f;
}

// ---------------------------------------------------------------------------
// In-register 16-point inverse DFT: y[m] = sum_a z[a] e^{+2pi i a m/16}.
// 4x4 decomposition (a = a0 + 4*a1, m = m0 + 4*m1), hardwired twiddles.
__device__ __forceinline__ void cmul(float& xr, float& xi, float cr, float ci) {
  float t = xr * cr - xi * ci;
  xi = xr * ci + xi * cr;
  xr = t;
}

__device__ __forceinline__ void idft16(float* zr, float* zi) {
  float vr[16], vi[16];
  // layer 1: radix-4 over a1 on (a0, a0+4, a0+8, a0+12) -> v[a0*4 + m0]
#pragma unroll
  for (int a0 = 0; a0 < 4; ++a0) {
    float z0r = zr[a0],      z0i = zi[a0];
    float z1r = zr[a0 + 4],  z1i = zi[a0 + 4];
    float z2r = zr[a0 + 8],  z2i = zi[a0 + 8];
    float z3r = zr[a0 + 12], z3i = zi[a0 + 12];
    float t0r = z0r + z2r, t0i = z0i + z2i;
    float t1r = z0r - z2r, t1i = z0i - z2i;
    float t2r = z1r + z3r, t2i = z1i + z3i;
    float t3r = z3i - z1i, t3i = z1r - z3r;   // +i*(z1 - z3)
    vr[a0 * 4 + 0] = t0r + t2r; vi[a0 * 4 + 0] = t0i + t2i;
    vr[a0 * 4 + 1] = t1r + t3r; vi[a0 * 4 + 1] = t1i + t3i;
    vr[a0 * 4 + 2] = t0r - t2r; vi[a0 * 4 + 2] = t0i - t2i;
    vr[a0 * 4 + 3] = t1r - t3r; vi[a0 * 4 + 3] = t1i - t3i;
  }
  // twiddles v[a0,m0] *= e^{2pi i a0 m0/16}  (t = a0*m0)
  cmul(vr[5],  vi[5],  C16C, C16S);            // t=1
  cmul(vr[6],  vi[6],  C8P,  C8P);             // t=2
  cmul(vr[7],  vi[7],  C16S, C16C);            // t=3
  cmul(vr[9],  vi[9],  C8P,  C8P);             // t=2
  { float t = vr[10]; vr[10] = -vi[10]; vi[10] = t; }  // t=4 -> *i
  cmul(vr[11], vi[11], -C8P, C8P);             // t=6
  cmul(vr[13], vi[13], C16S, C16C);            // t=3
  cmul(vr[14], vi[14], -C8P, C8P);             // t=6
  cmul(vr[15], vi[15], -C16C, -C16S);          // t=9
  // layer 2: radix-4 over a0 for each m0 -> out[m0 + 4*m1]
#pragma unroll
  for (int m0 = 0; m0 < 4; ++m0) {
    float z0r = vr[0 + m0],  z0i = vi[0 + m0];
    float z1r = vr[4 + m0],  z1i = vi[4 + m0];
    float z2r = vr[8 + m0],  z2i = vi[8 + m0];
    float z3r = vr[12 + m0], z3i = vi[12 + m0];
    float t0r = z0r + z2r, t0i = z0i + z2i;
    float t1r = z0r - z2r, t1i = z0i - z2i;
    float t2r = z1r + z3r, t2i = z1i + z3i;
    float t3r = z3i - z1i, t3i = z1r - z3r;   // +i*(z1 - z3)
    zr[m0 + 0]  = t0r + t2r; zi[m0 + 0]  = t0i + t2i;
    zr[m0 + 4]  = t1r + t3r; zi[m0 + 4]  = t1i + t3i;
    zr[m0 + 8]  = t0r - t2r; zi[m0 + 8]  = t0i - t2i;
    zr[m0 + 12] = t1r - t3r; zi[m0 + 12] = t1i - t3i;
  }
}

// Chained twiddle: z[q] *= cis(q*step), q=1..15 (recurrence off one sincos).
__device__ __forceinline__ void twiddle_chain(float* zr, float* zi, float step) {
  float sA, cA; __sincosf(step, &sA, &cA);
  float cr = cA, ci = sA;
  cmul(zr[1], zi[1], cr, ci);
#pragma unroll
  for (int q = 2; q < 16; ++q) {
    float nr = cr * cA - ci * sA;
    ci = cr * sA + ci * cA;
    cr = nr;
    cmul(zr[q], zi[q], cr, ci);
  }
}

// ---------------------------------------------------------------------------
// Fused trans+IFFT, radix-16^3 register formulation.
// One 4096-pt complex IFFT per frame-PAIR yields TWO real frames (a=Re, b=Im).
// Inputs read directly from re/im [B, C_IN, T_FR] fp32 (gather, stride 1380B);
// XCD-chunked swizzle (b = bid&7) keeps the 8 line-sharing j-blocks on one
// XCD's L2. Mag/phase recombine (r' = x*sqrt(r^2+i^2)*rsqrt(x^2+i^2), x=r+eps)
// and hermitian combine are fused into the load:
//   k in [1,2047]: Z[k] = (ar - bi) + i(ai + br); Z[4096-k] = (ar + bi) + i(br - ai)
//   Z[0] = ar0 + i*br0,  Z[2048] = arN + i*brN   (imag at DC/Nyquist dropped,
//   matching the reference's zero-norm sin rows)
// Decomposition: k = k0 + 16 k1 + 256 k2, n = n0 + 16 n1 + 256 n2.
//   stage1 (thread k0+16k1, regs over k2): IDFT16_k2
//   stage2 (thread k0+16n0): *cis(2pi n0 k1/256), IDFT16_k1
//   stage3 (thread n0+16n1): *cis(2pi (n0+16n1) k0/4096), IDFT16_k0
// LDS: two 17-float-padded [16x16x16] exchange buffers (34 KiB), 3 barriers.
__global__ __launch_bounds__(256, 4) void ifft_frames(const float* __restrict__ re,
                                                      const float* __restrict__ im,
                                                      unsigned short* __restrict__ Fr) {
  __shared__ float LR[4352];   // 17*16*16
  __shared__ float LI[4352];
  const int tid = threadIdx.x;
  const int bid = blockIdx.x + NPAIR * blockIdx.y;
  const int b = bid & 7;                      // XCD-chunked: one batch per XCD
  const int j = bid >> 3;                     // 0..172, consecutive on one XCD
  const int t2 = 2 * j;
  const int ta = b * T_FR + t2;               // frame a (always valid)
  const bool hasb = (t2 + 1) < T_FR;          // frame b exists (t=344 leftover)

  float zr[16], zi[16];
  // ---- gather + recombine + hermitian combine: z[q] = Z[tid + 256*q]
#pragma unroll
  for (int q = 0; q < 16; ++q) {
    int n = tid + 256 * q;
    int k = (n <= 2048) ? n : (4096 - n);
    unsigned off = ((unsigned)b * C_IN + (unsigned)k) * T_FR + t2;
    float ra = re[off], ia = im[off];
    float rb = 0.f, ib = 0.f;
    if (hasb) { rb = re[off + 1]; ib = im[off + 1]; }
    float xa = ra + 1.1920929e-7f;
    float inva = __builtin_amdgcn_sqrtf(ra * ra + ia * ia) *
                 __builtin_amdgcn_rsqf(fmaxf(xa * xa + ia * ia, 1e-35f));
    float ar = xa * inva, ai = ia * inva;     // mag*cos(phase), mag*sin(phase)
    float xb = rb + 1.1920929e-7f;
    float invb = __builtin_amdgcn_sqrtf(rb * rb + ib * ib) *
                 __builtin_amdgcn_rsqf(fmaxf(xb * xb + ib * ib, 1e-35f));
    float br = xb * invb, bi = ib * invb;
    bool dc  = (n == 0) | (n == 2048);        // DC/Nyquist: drop imag parts
    bool mir = n > 2048;
    float zzr = mir ? (ar + bi) : (ar - bi);
    float zzi = mir ? (br - ai) : (ai + br);
    zr[q] = dc ? ar : zzr;
    zi[q] = dc ? br : zzi;
  }
  // ---- stage 1: IDFT16 over k2 (no twiddle); write A[k0,k1,n0]
  idft16(zr, zi);
  {
    int base = (tid >> 4) + 17 * (tid & 15);   // k1 + 17*k0
#pragma unroll
    for (int m = 0; m < 16; ++m) { LR[base + 272 * m] = zr[m]; LI[base + 272 * m] = zi[m]; }
  }
  __syncthreads();
  // ---- stage 2: thread (k0=tid&15, n0=tid>>4); read A over k1 (contiguous)
  {
    int base = 17 * (tid & 15) + 272 * (tid >> 4);
#pragma unroll
    for (int q = 0; q < 16; ++q) { zr[q] = LR[base + q]; zi[q] = LI[base + q]; }
  }
  __syncthreads();
  twiddle_chain(zr, zi, (float)(tid >> 4) * TW256);   // cis(2pi n0 k1/256)
  idft16(zr, zi);
  {
    int base = (tid & 15) + 17 * (tid >> 4);   // k0 + 17*n0
#pragma unroll
    for (int m = 0; m < 16; ++m) { LR[base + 272 * m] = zr[m]; LI[base + 272 * m] = zi[m]; }
  }
  __syncthreads();
  // ---- stage 3: thread (n0=tid&15, n1=tid>>4); read B over k0 (contiguous)
  {
    int base = 17 * (tid & 15) + 272 * (tid >> 4);
#pragma unroll
    for (int q = 0; q < 16; ++q) { zr[q] = LR[base + q]; zi[q] = LI[base + q]; }
  }
  twiddle_chain(zr, zi, (float)tid * TW);      // cis(2pi (n0+16n1) k0/4096), n0+16n1 == tid
  idft16(zr, zi);
  // ---- windowed bf16 pack + store: sample n = 256*m + tid; a = Re, b = Im.
  // Pair packing via shfl with lane^1: even lanes store frame a dwords,
  // odd lanes store frame b dwords (win/256 folded into the store).
  unsigned int* da = (unsigned int*)(Fr + (size_t)ta * NFFT);
  unsigned int* db = (unsigned int*)(Fr + (size_t)(ta + 1) * NFFT);
  const bool even = (tid & 1) == 0;
#pragma unroll
  for (int m = 0; m < 16; ++m) {
    int n = 256 * m + tid;
    float w = (0.5f - 0.5f * __cosf((float)n * TW)) * 0.00390625f;   // win/256
    float va = zr[m] * w, vb = zi[m] * w;
    float xa = __shfl_xor(va, 1);
    float xb = __shfl_xor(vb, 1);
    unsigned int pa = ((unsigned int)f2b(xa) << 16) | f2b(va);  // even: (n, n+1)
    unsigned int pb = ((unsigned int)f2b(vb) << 16) | f2b(xb);  // odd:  (n-1, n)
    int dw = 128 * m + (tid >> 1);
    if (even)      da[dw] = pa;
    else if (hasb) db[dw] = pb;
  }
}

// ---------------------------------------------------------------------------
// Overlap-add gather, x4 vectorized. Quads are 4-aligned and boundaries are at
// multiples of 1024, so all 4 outputs of a quad share the same tap range ->
// one ushort4 load per tap, float4 store. Interior window_sum == 1.5 exactly
// (4 phase-shifted hann^2 sum), so wsi is the constant W_INT except in the
// first/last ~1.8k samples (those load wsi). XCD-chunked swizzle (b = bid&7)
// matches the ifft producer's mapping -> Fr slice is L2-resident per XCD.
__global__ void ola(const unsigned short* __restrict__ Fr, const float* __restrict__ wsi,
                    float* __restrict__ out, int length) {
  const int bid = blockIdx.x + 345 * blockIdx.y;
  const int b = bid & 7;
  const int pblk = bid >> 3;                  // 0..344, consecutive on one XCD
  int q = pblk * 256 + threadIdx.x;
  int p4 = q * 4;
  if (p4 >= length) return;
  int s0 = (NFFT / 2) + p4;
  int tlo = (s0 - 3072) >> 10;
  tlo = tlo < 0 ? 0 : tlo;
  int thi = s0 >> 10;
  thi = thi > (T_FR - 1) ? (T_FR - 1) : thi;
  float a0 = 0.f, a1 = 0.f, a2 = 0.f, a3 = 0.f;
  for (int t = tlo; t <= thi; ++t) {
    const unsigned short* fp = Fr + ((size_t)(b * T_FR + t)) * NFFT + (s0 - (t << 10));
    ushort4 v = *(const ushort4*)fp;          // 8B aligned: s0 % 4 == 0
    a0 += b2f(v.x); a1 += b2f(v.y); a2 += b2f(v.z); a3 += b2f(v.w);
  }
  float4 wv;
  if (s0 >= 3072 && s0 <= 353276) {           // interior: analytic wsi
    wv.x = W_INT; wv.y = W_INT; wv.z = W_INT; wv.w = W_INT;
  } else {
    wv = *(const float4*)(wsi + s0);
  }
  float4 o; o.x = a0 * wv.x; o.y = a1 * wv.y; o.z = a2 * wv.z; o.w = a3 * wv.w;
  *(float4*)(out + (size_t)b * length + p4) = o;
}

// ---------------------------------------------------------------------------
extern "C" void kernel_launch(void* const* d_in, const int* in_sizes, int n_in,
                              void* d_out, int out_size, void* d_ws, size_t ws_size,
                              hipStream_t stream) {
  const float* re  = (const float*)d_in[0];
  const float* im  = (const float*)d_in[1];
  // d_in[2] (inverse_basis) unused — spectral identity HW-verified previously.
  const float* wsi = (const float*)d_in[3];
  float* out = (float*)d_out;
  const int length = out_size / B_SZ;   // 352800

  // Workspace (22.6 MB): Fr bf16 [MFR x 4096]. (spec intermediate eliminated)
  unsigned short* Fr = (unsigned short*)d_ws;

  ifft_frames<<<dim3(NPAIR, B_SZ), 256, 0, stream>>>(re, im, Fr);
  ola<<<dim3(345, B_SZ), 256, 0, stream>>>(Fr, wsi, out, length);
}

// Round 3
// 168.737 us; speedup vs baseline: 1.3294x; 1.3294x over previous
//
#include <hip/hip_runtime.h>
#include <cstdint>
#include <cstddef>

// Problem constants (fixed by the reference file)
#define B_SZ  8
#define C_IN  2049          // N_FFT/2+1
#define T_FR  345           // MAX_FRAMES
#define NFFT  4096
#define HOPSZ 1024
#define MFR   2760          // B_SZ*T_FR frames
#define NPAIR 173           // ceil(345/2) frame-pairs per batch
#define TW    1.5339807878856412e-3f   // 2*pi/4096
#define TW256 2.4543692606170259e-2f   // 2*pi/256
// Interior window_sum is exactly 1.5 (sum of 4 phase-shifted hann^2):
// wsi = 4096/(1.5*1024 + 1e-8)  [HW-verified round 2]
#define W_INT 2.6666666666484f

// e^{i*pi/8} family for the in-register 16-pt IDFT
#define C8P   0.70710678118654752f
#define C16C  0.92387953251128676f
#define C16S  0.38268343236508977f

typedef float f4 __attribute__((ext_vector_type(4)));

__device__ __forceinline__ unsigned short f2b(float f) {
  union { float f; unsigned int u; } v; v.f = f;
  unsigned int r = v.u + 0x7fffu + ((v.u >> 16) & 1u);  // RNE to bf16
  return (unsigned short)(r >> 16);
}
__device__ __forceinline__ float b2f(unsigned int h) {
  union { unsigned int u; float f; } v; v.u = h << 16;
  return v.f;
}

// ---------------------------------------------------------------------------
// trans: [B, C_IN, T_FR] re/im fp32 -> spec[(b*T+t)*2049 + c] packed bf16 pair
// (re low 16, im high 16). LDS 64x64 tile transpose; fast-math recombine:
// r' = x*sqrt(r^2+i^2)*rsqrt(x^2+i^2), x = r+eps  (bf16 target, approx ok).
// 1D grid, b = bid&7: all of batch b's blocks land on XCD b (round-robin
// dispatch) so the spec slice (2.83 MB) is L2-resident for ifft_frames.
__global__ void trans(const float* __restrict__ re, const float* __restrict__ im,
                      unsigned int* __restrict__ spec) {
  __shared__ float tr[64][65];
  __shared__ float ti[64][65];
  const int tid  = threadIdx.x;
  const int bid  = blockIdx.x;
  const int b    = bid & 7;                 // batch -> XCD
  const int tile = bid >> 3;                // 0..197 per batch
  const int t0 = (tile % 6) * 64;
  const int c0 = (tile / 6) * 64;
#pragma unroll
  for (int pass = 0; pass < 16; ++pass) {
    int idx = pass * 256 + tid;
    int tt = idx & 63, cc = idx >> 6;
    int c = c0 + cc, t = t0 + tt;
    float rp = 0.f, ip = 0.f;
    if (c < C_IN && t < T_FR) {
      size_t off = ((size_t)b * C_IN + c) * T_FR + t;
      float r = re[off], i = im[off];
      float x  = r + 1.1920929e-7f;            // real + eps (phase arg)
      float r2 = r * r + i * i;
      float h2 = fmaxf(x * x + i * i, 1e-35f);
      float inv = __builtin_amdgcn_sqrtf(r2) * __builtin_amdgcn_rsqf(h2);
      rp = x * inv;                             // mag*cos(phase)
      ip = i * inv;                             // mag*sin(phase)
    }
    tr[cc][tt] = rp;
    ti[cc][tt] = ip;
  }
  __syncthreads();
#pragma unroll
  for (int pass = 0; pass < 16; ++pass) {
    int idx = pass * 256 + tid;
    int kk = idx & 63, tt = idx >> 6;
    int c = c0 + kk, t = t0 + tt;
    if (c < C_IN && t < T_FR) {
      size_t mrow = (size_t)b * T_FR + t;
      unsigned int pk = ((unsigned int)f2b(ti[kk][tt]) << 16) | f2b(tr[kk][tt]);
      spec[mrow * C_IN + c] = pk;
    }
  }
}

// ---------------------------------------------------------------------------
// In-register 16-point inverse DFT: y[m] = sum_a z[a] e^{+2pi i a m/16}.
// 4x4 decomposition (a = a0 + 4*a1, m = m0 + 4*m1), hardwired twiddles.
__device__ __forceinline__ void cmul(float& xr, float& xi, float cr, float ci) {
  float t = xr * cr - xi * ci;
  xi = xr * ci + xi * cr;
  xr = t;
}

__device__ __forceinline__ void idft16(float* zr, float* zi) {
  float vr[16], vi[16];
  // layer 1: radix-4 over a1 on (a0, a0+4, a0+8, a0+12) -> v[a0*4 + m0]
#pragma unroll
  for (int a0 = 0; a0 < 4; ++a0) {
    float z0r = zr[a0],      z0i = zi[a0];
    float z1r = zr[a0 + 4],  z1i = zi[a0 + 4];
    float z2r = zr[a0 + 8],  z2i = zi[a0 + 8];
    float z3r = zr[a0 + 12], z3i = zi[a0 + 12];
    float t0r = z0r + z2r, t0i = z0i + z2i;
    float t1r = z0r - z2r, t1i = z0i - z2i;
    float t2r = z1r + z3r, t2i = z1i + z3i;
    float t3r = z3i - z1i, t3i = z1r - z3r;   // +i*(z1 - z3)
    vr[a0 * 4 + 0] = t0r + t2r; vi[a0 * 4 + 0] = t0i + t2i;
    vr[a0 * 4 + 1] = t1r + t3r; vi[a0 * 4 + 1] = t1i + t3i;
    vr[a0 * 4 + 2] = t0r - t2r; vi[a0 * 4 + 2] = t0i - t2i;
    vr[a0 * 4 + 3] = t1r - t3r; vi[a0 * 4 + 3] = t1i - t3i;
  }
  // twiddles v[a0,m0] *= e^{2pi i a0 m0/16}  (t = a0*m0)
  cmul(vr[5],  vi[5],  C16C, C16S);            // t=1
  cmul(vr[6],  vi[6],  C8P,  C8P);             // t=2
  cmul(vr[7],  vi[7],  C16S, C16C);            // t=3
  cmul(vr[9],  vi[9],  C8P,  C8P);             // t=2
  { float t = vr[10]; vr[10] = -vi[10]; vi[10] = t; }  // t=4 -> *i
  cmul(vr[11], vi[11], -C8P, C8P);             // t=6
  cmul(vr[13], vi[13], C16S, C16C);            // t=3
  cmul(vr[14], vi[14], -C8P, C8P);             // t=6
  cmul(vr[15], vi[15], -C16C, -C16S);          // t=9
  // layer 2: radix-4 over a0 for each m0 -> out[m0 + 4*m1]
#pragma unroll
  for (int m0 = 0; m0 < 4; ++m0) {
    float z0r = vr[0 + m0],  z0i = vi[0 + m0];
    float z1r = vr[4 + m0],  z1i = vi[4 + m0];
    float z2r = vr[8 + m0],  z2i = vi[8 + m0];
    float z3r = vr[12 + m0], z3i = vi[12 + m0];
    float t0r = z0r + z2r, t0i = z0i + z2i;
    float t1r = z0r - z2r, t1i = z0i - z2i;
    float t2r = z1r + z3r, t2i = z1i + z3i;
    float t3r = z3i - z1i, t3i = z1r - z3r;   // +i*(z1 - z3)
    zr[m0 + 0]  = t0r + t2r; zi[m0 + 0]  = t0i + t2i;
    zr[m0 + 4]  = t1r + t3r; zi[m0 + 4]  = t1i + t3i;
    zr[m0 + 8]  = t0r - t2r; zi[m0 + 8]  = t0i - t2i;
    zr[m0 + 12] = t1r - t3r; zi[m0 + 12] = t1i - t3i;
  }
}

// Chained twiddle: z[q] *= cis(q*step), q=1..15 (recurrence off one sincos).
__device__ __forceinline__ void twiddle_chain(float* zr, float* zi, float step) {
  float sA, cA; __sincosf(step, &sA, &cA);
  float cr = cA, ci = sA;
  cmul(zr[1], zi[1], cr, ci);
#pragma unroll
  for (int q = 2; q < 16; ++q) {
    float nr = cr * cA - ci * sA;
    ci = cr * sA + ci * cA;
    cr = nr;
    cmul(zr[q], zi[q], cr, ci);
  }
}

// ---------------------------------------------------------------------------
// Real-pair IFFT, radix-16^3 register formulation (reads packed-bf16 spec,
// coalesced). One 4096-pt complex IFFT yields TWO real frames (a=Re, b=Im).
// Hermitian combine in the register load (spec row is L1/L2-hot):
//   k in [1,2047]: Z[k] = (ar - bi) + i(ai + br); Z[4096-k] = (ar + bi) + i(br - ai)
//   Z[0] = ar0 + i*br0,  Z[2048] = arN + i*brN
// Decomposition: k = k0 + 16 k1 + 256 k2, n = n0 + 16 n1 + 256 n2.
// LDS: two 17-float-padded [16x16x16] exchange buffers (34 KiB), 3 barriers.
// 1D grid, b = bid&7 matches trans/ola -> spec reads & Fr writes stay on XCD b.
__global__ __launch_bounds__(256, 4) void ifft_frames(const unsigned int* __restrict__ spec,
                                                      unsigned short* __restrict__ Fr) {
  __shared__ float LR[4352];   // 17*16*16
  __shared__ float LI[4352];
  const int tid = threadIdx.x;
  const int bid = blockIdx.x;
  const int b = bid & 7;                      // batch -> XCD
  const int j = bid >> 3;                     // 0..172
  const int ta = b * T_FR + 2 * j;            // frame a (always valid)
  const bool hasb = (2 * j + 1) < T_FR;       // frame b exists (t=344 leftover)
  const unsigned int* spa = spec + (size_t)ta * C_IN;
  const unsigned int* spb = spa + C_IN;

  float zr[16], zi[16];
  // ---- load + hermitian combine: z[q] = Z[tid + 256*q]
#pragma unroll
  for (int q = 0; q < 16; ++q) {
    int n = tid + 256 * q;
    int k = (n <= 2048) ? n : (4096 - n);
    unsigned int va = spa[k];
    unsigned int vb = hasb ? spb[k] : 0u;
    float ar = b2f(va & 0xffffu), ai = b2f(va >> 16);
    float br = b2f(vb & 0xffffu), bi = b2f(vb >> 16);
    bool dc  = (n == 0) | (n == 2048);        // DC/Nyquist: drop imag parts
    bool mir = n > 2048;
    float zzr = mir ? (ar + bi) : (ar - bi);
    float zzi = mir ? (br - ai) : (ai + br);
    zr[q] = dc ? ar : zzr;
    zi[q] = dc ? br : zzi;
  }
  // ---- stage 1: IDFT16 over k2 (no twiddle); write A[k0,k1,n0]
  idft16(zr, zi);
  {
    int base = (tid >> 4) + 17 * (tid & 15);   // k1 + 17*k0
#pragma unroll
    for (int m = 0; m < 16; ++m) { LR[base + 272 * m] = zr[m]; LI[base + 272 * m] = zi[m]; }
  }
  __syncthreads();
  // ---- stage 2: thread (k0=tid&15, n0=tid>>4); read A over k1 (contiguous)
  {
    int base = 17 * (tid & 15) + 272 * (tid >> 4);
#pragma unroll
    for (int q = 0; q < 16; ++q) { zr[q] = LR[base + q]; zi[q] = LI[base + q]; }
  }
  __syncthreads();
  twiddle_chain(zr, zi, (float)(tid >> 4) * TW256);   // cis(2pi n0 k1/256)
  idft16(zr, zi);
  {
    int base = (tid & 15) + 17 * (tid >> 4);   // k0 + 17*n0
#pragma unroll
    for (int m = 0; m < 16; ++m) { LR[base + 272 * m] = zr[m]; LI[base + 272 * m] = zi[m]; }
  }
  __syncthreads();
  // ---- stage 3: thread (n0=tid&15, n1=tid>>4); read B over k0 (contiguous)
  {
    int base = 17 * (tid & 15) + 272 * (tid >> 4);
#pragma unroll
    for (int q = 0; q < 16; ++q) { zr[q] = LR[base + q]; zi[q] = LI[base + q]; }
  }
  twiddle_chain(zr, zi, (float)tid * TW);      // cis(2pi (n0+16n1) k0/4096), n0+16n1 == tid
  idft16(zr, zi);
  // ---- windowed bf16 pack + store: sample n = 256*m + tid; a = Re, b = Im.
  // Pair packing via shfl with lane^1: even lanes store frame a dwords,
  // odd lanes store frame b dwords (win/256 folded into the store).
  unsigned int* da = (unsigned int*)(Fr + (size_t)ta * NFFT);
  unsigned int* db = (unsigned int*)(Fr + (size_t)(ta + 1) * NFFT);
  const bool even = (tid & 1) == 0;
#pragma unroll
  for (int m = 0; m < 16; ++m) {
    int n = 256 * m + tid;
    float w = (0.5f - 0.5f * __cosf((float)n * TW)) * 0.00390625f;   // win/256
    float va = zr[m] * w, vb = zi[m] * w;
    float xa = __shfl_xor(va, 1);
    float xb = __shfl_xor(vb, 1);
    unsigned int pa = ((unsigned int)f2b(xa) << 16) | f2b(va);  // even: (n, n+1)
    unsigned int pb = ((unsigned int)f2b(vb) << 16) | f2b(xb);  // odd:  (n-1, n)
    int dw = 128 * m + (tid >> 1);
    if (even)      da[dw] = pa;
    else if (hasb) db[dw] = pb;
  }
}

// ---------------------------------------------------------------------------
// Overlap-add gather, x4 vectorized. Quads are 4-aligned and boundaries are at
// multiples of 1024, so all 4 outputs of a quad share the same tap range ->
// one ushort4 load per tap, float4 store. Interior window_sum == 1.5 exactly
// (4 phase-shifted hann^2), so wsi is the constant W_INT except in the
// first/last ~1.8k samples (those load wsi). 1D grid, b = bid&7 matches the
// ifft producer's mapping -> Fr slice is L2-resident per XCD.
__global__ void ola(const unsigned short* __restrict__ Fr, const float* __restrict__ wsi,
                    float* __restrict__ out, int length) {
  const int bid = blockIdx.x;
  const int b = bid & 7;                      // batch -> XCD
  const int pblk = bid >> 3;                  // 0..344
  int q = pblk * 256 + threadIdx.x;
  int p4 = q * 4;
  if (p4 >= length) return;
  int s0 = (NFFT / 2) + p4;
  int tlo = (s0 - 3072) >> 10;
  tlo = tlo < 0 ? 0 : tlo;
  int thi = s0 >> 10;
  thi = thi > (T_FR - 1) ? (T_FR - 1) : thi;
  float a0 = 0.f, a1 = 0.f, a2 = 0.f, a3 = 0.f;
  for (int t = tlo; t <= thi; ++t) {
    const unsigned short* fp = Fr + ((size_t)(b * T_FR + t)) * NFFT + (s0 - (t << 10));
    ushort4 v = *(const ushort4*)fp;          // 8B aligned: s0 % 4 == 0
    a0 += b2f(v.x); a1 += b2f(v.y); a2 += b2f(v.z); a3 += b2f(v.w);
  }
  float4 wv;
  if (s0 >= 3072 && s0 <= 353276) {           // interior: analytic wsi
    wv.x = W_INT; wv.y = W_INT; wv.z = W_INT; wv.w = W_INT;
  } else {
    wv = *(const float4*)(wsi + s0);
  }
  float4 o; o.x = a0 * wv.x; o.y = a1 * wv.y; o.z = a2 * wv.z; o.w = a3 * wv.w;
  *(float4*)(out + (size_t)b * length + p4) = o;
}

// ---------------------------------------------------------------------------
extern "C" void kernel_launch(void* const* d_in, const int* in_sizes, int n_in,
                              void* d_out, int out_size, void* d_ws, size_t ws_size,
                              hipStream_t stream) {
  const float* re  = (const float*)d_in[0];
  const float* im  = (const float*)d_in[1];
  // d_in[2] (inverse_basis) unused — spectral identity HW-verified previously.
  const float* wsi = (const float*)d_in[3];
  float* out = (float*)d_out;
  const int length = out_size / B_SZ;   // 352800

  // Workspace (45.2 MB): spec packed-bf16 [MFR x 2049], Fr bf16 [MFR x 4096].
  unsigned int*   spec = (unsigned int*)d_ws;
  unsigned short* Fr   = (unsigned short*)(spec + (size_t)MFR * C_IN);

  // All grids are multiples of 8; b = bid&7 keeps each batch on one XCD
  // across the whole producer->consumer chain (spec and Fr L2 residency).
  trans<<<dim3(8 * 198), 256, 0, stream>>>(re, im, spec);        // 198 tiles/batch
  ifft_frames<<<dim3(8 * NPAIR), 256, 0, stream>>>(spec, Fr);    // 173 pairs/batch
  ola<<<dim3(8 * 345), 256, 0, stream>>>(Fr, wsi, out, length);  // 345 blocks/batch
}

// Round 4
// 167.471 us; speedup vs baseline: 1.3395x; 1.0076x over previous
//
#include <hip/hip_runtime.h>
#include <cstdint>
#include <cstddef>

// Problem constants (fixed by the reference file)
#define B_SZ  8
#define C_IN  2049          // N_FFT/2+1
#define T_FR  345           // MAX_FRAMES
#define NFFT  4096
#define HOPSZ 1024
#define MFR   2760          // B_SZ*T_FR frames
#define NPAIR 173           // ceil(345/2) frame-pairs per batch
#define TW    1.5339807878856412e-3f   // 2*pi/4096
#define TW256 2.4543692606170259e-2f   // 2*pi/256
// Interior window_sum is exactly 1.5 (sum of 4 phase-shifted hann^2):
// wsi = 4096/(1.5*1024 + 1e-8)  [HW-verified round 2/3]
#define W_INT 2.6666666666484f

// e^{i*pi/8} family for the in-register 16-pt IDFT
#define C8P   0.70710678118654752f
#define C16C  0.92387953251128676f
#define C16S  0.38268343236508977f

__device__ __forceinline__ unsigned short f2b(float f) {
  union { float f; unsigned int u; } v; v.f = f;
  unsigned int r = v.u + 0x7fffu + ((v.u >> 16) & 1u);  // RNE to bf16
  return (unsigned short)(r >> 16);
}
__device__ __forceinline__ float b2f(unsigned int h) {
  union { unsigned int u; float f; } v; v.u = h << 16;
  return v.f;
}

// ---------------------------------------------------------------------------
// trans: [B, C_IN, T_FR] re/im fp32 -> spec[(b*T+t)*2049 + c] packed bf16 pair
// (re low 16, im high 16). LDS 64x64 tile transpose; fast-math recombine.
// 1D grid, b = bid&7 (batch -> XCD). Tiles are T-MAJOR (t-block varies
// slowest): the last-written spec rows are high-t, so the REVERSED ifft
// (j descending) reads freshest-first under L2 LRU.
__global__ __launch_bounds__(256) void trans(const float* __restrict__ re,
                                             const float* __restrict__ im,
                                             unsigned int* __restrict__ spec) {
  __shared__ float tr[64][65];
  __shared__ float ti[64][65];
  const int tid  = threadIdx.x;
  const int bid  = blockIdx.x;
  const int b    = bid & 7;                 // batch -> XCD
  const int tile = bid >> 3;                // 0..197 per batch
  const int t0 = (tile / 33) * 64;          // t-major: t-block slowest
  const int c0 = (tile % 33) * 64;
#pragma unroll
  for (int pass = 0; pass < 16; ++pass) {
    int idx = pass * 256 + tid;
    int tt = idx & 63, cc = idx >> 6;
    int c = c0 + cc, t = t0 + tt;
    float rp = 0.f, ip = 0.f;
    if (c < C_IN && t < T_FR) {
      size_t off = ((size_t)b * C_IN + c) * T_FR + t;
      float r = re[off], i = im[off];
      float x  = r + 1.1920929e-7f;            // real + eps (phase arg)
      float r2 = r * r + i * i;
      float h2 = fmaxf(x * x + i * i, 1e-35f);
      float inv = __builtin_amdgcn_sqrtf(r2) * __builtin_amdgcn_rsqf(h2);
      rp = x * inv;                             // mag*cos(phase)
      ip = i * inv;                             // mag*sin(phase)
    }
    tr[cc][tt] = rp;
    ti[cc][tt] = ip;
  }
  __syncthreads();
#pragma unroll
  for (int pass = 0; pass < 16; ++pass) {
    int idx = pass * 256 + tid;
    int kk = idx & 63, tt = idx >> 6;
    int c = c0 + kk, t = t0 + tt;
    if (c < C_IN && t < T_FR) {
      size_t mrow = (size_t)b * T_FR + t;
      unsigned int pk = ((unsigned int)f2b(ti[kk][tt]) << 16) | f2b(tr[kk][tt]);
      spec[mrow * C_IN + c] = pk;
    }
  }
}

// ---------------------------------------------------------------------------
// In-register 16-point inverse DFT: y[m] = sum_a z[a] e^{+2pi i a m/16}.
// 4x4 decomposition (a = a0 + 4*a1, m = m0 + 4*m1), hardwired twiddles.
__device__ __forceinline__ void cmul(float& xr, float& xi, float cr, float ci) {
  float t = xr * cr - xi * ci;
  xi = xr * ci + xi * cr;
  xr = t;
}

__device__ __forceinline__ void idft16(float* zr, float* zi) {
  float vr[16], vi[16];
  // layer 1: radix-4 over a1 on (a0, a0+4, a0+8, a0+12) -> v[a0*4 + m0]
#pragma unroll
  for (int a0 = 0; a0 < 4; ++a0) {
    float z0r = zr[a0],      z0i = zi[a0];
    float z1r = zr[a0 + 4],  z1i = zi[a0 + 4];
    float z2r = zr[a0 + 8],  z2i = zi[a0 + 8];
    float z3r = zr[a0 + 12], z3i = zi[a0 + 12];
    float t0r = z0r + z2r, t0i = z0i + z2i;
    float t1r = z0r - z2r, t1i = z0i - z2i;
    float t2r = z1r + z3r, t2i = z1i + z3i;
    float t3r = z3i - z1i, t3i = z1r - z3r;   // +i*(z1 - z3)
    vr[a0 * 4 + 0] = t0r + t2r; vi[a0 * 4 + 0] = t0i + t2i;
    vr[a0 * 4 + 1] = t1r + t3r; vi[a0 * 4 + 1] = t1i + t3i;
    vr[a0 * 4 + 2] = t0r - t2r; vi[a0 * 4 + 2] = t0i - t2i;
    vr[a0 * 4 + 3] = t1r - t3r; vi[a0 * 4 + 3] = t1i - t3i;
  }
  // twiddles v[a0,m0] *= e^{2pi i a0 m0/16}  (t = a0*m0)
  cmul(vr[5],  vi[5],  C16C, C16S);            // t=1
  cmul(vr[6],  vi[6],  C8P,  C8P);             // t=2
  cmul(vr[7],  vi[7],  C16S, C16C);            // t=3
  cmul(vr[9],  vi[9],  C8P,  C8P);             // t=2
  { float t = vr[10]; vr[10] = -vi[10]; vi[10] = t; }  // t=4 -> *i
  cmul(vr[11], vi[11], -C8P, C8P);             // t=6
  cmul(vr[13], vi[13], C16S, C16C);            // t=3
  cmul(vr[14], vi[14], -C8P, C8P);             // t=6
  cmul(vr[15], vi[15], -C16C, -C16S);          // t=9
  // layer 2: radix-4 over a0 for each m0 -> out[m0 + 4*m1]
#pragma unroll
  for (int m0 = 0; m0 < 4; ++m0) {
    float z0r = vr[0 + m0],  z0i = vi[0 + m0];
    float z1r = vr[4 + m0],  z1i = vi[4 + m0];
    float z2r = vr[8 + m0],  z2i = vi[8 + m0];
    float z3r = vr[12 + m0], z3i = vi[12 + m0];
    float t0r = z0r + z2r, t0i = z0i + z2i;
    float t1r = z0r - z2r, t1i = z0i - z2i;
    float t2r = z1r + z3r, t2i = z1i + z3i;
    float t3r = z3i - z1i, t3i = z1r - z3r;   // +i*(z1 - z3)
    zr[m0 + 0]  = t0r + t2r; zi[m0 + 0]  = t0i + t2i;
    zr[m0 + 4]  = t1r + t3r; zi[m0 + 4]  = t1i + t3i;
    zr[m0 + 8]  = t0r - t2r; zi[m0 + 8]  = t0i - t2i;
    zr[m0 + 12] = t1r - t3r; zi[m0 + 12] = t1i - t3i;
  }
}

// Chained twiddle: z[q] *= cis(q*step), q=1..15 (recurrence off one sincos).
__device__ __forceinline__ void twiddle_chain(float* zr, float* zi, float step) {
  float sA, cA; __sincosf(step, &sA, &cA);
  float cr = cA, ci = sA;
  cmul(zr[1], zi[1], cr, ci);
#pragma unroll
  for (int q = 2; q < 16; ++q) {
    float nr = cr * cA - ci * sA;
    ci = cr * sA + ci * cA;
    cr = nr;
    cmul(zr[q], zi[q], cr, ci);
  }
}

// ---------------------------------------------------------------------------
// Real-pair IFFT, radix-16^3 register formulation (reads packed-bf16 spec,
// coalesced). One 4096-pt complex IFFT yields TWO real frames (a=Re, b=Im).
// Hermitian combine in the register load:
//   k in [1,2047]: Z[k] = (ar - bi) + i(ai + br); Z[4096-k] = (ar + bi) + i(br - ai)
//   Z[0] = ar0 + i*br0,  Z[2048] = arN + i*brN
// Decomposition: k = k0 + 16 k1 + 256 k2, n = n0 + 16 n1 + 256 n2.
// LDS: two 17-float-padded [16x16x16] exchange buffers (34 KiB), 3 barriers.
// 1D grid, b = bid&7; j REVERSED (172->0): reads trans's freshest spec rows
// first, and leaves low-t Fr freshest for ola's ascending read.
__global__ __launch_bounds__(256, 4) void ifft_frames(const unsigned int* __restrict__ spec,
                                                      unsigned short* __restrict__ Fr) {
  __shared__ float LR[4352];   // 17*16*16
  __shared__ float LI[4352];
  const int tid = threadIdx.x;
  const int bid = blockIdx.x;
  const int b = bid & 7;                      // batch -> XCD
  const int j = (NPAIR - 1) - (bid >> 3);     // 172..0 (reversed)
  const int ta = b * T_FR + 2 * j;            // frame a (always valid)
  const bool hasb = (2 * j + 1) < T_FR;       // frame b exists (t=344 leftover)
  const unsigned int* spa = spec + (size_t)ta * C_IN;
  const unsigned int* spb = spa + C_IN;

  float zr[16], zi[16];
  // ---- load + hermitian combine: z[q] = Z[tid + 256*q]
#pragma unroll
  for (int q = 0; q < 16; ++q) {
    int n = tid + 256 * q;
    int k = (n <= 2048) ? n : (4096 - n);
    unsigned int va = spa[k];
    unsigned int vb = hasb ? spb[k] : 0u;
    float ar = b2f(va & 0xffffu), ai = b2f(va >> 16);
    float br = b2f(vb & 0xffffu), bi = b2f(vb >> 16);
    bool dc  = (n == 0) | (n == 2048);        // DC/Nyquist: drop imag parts
    bool mir = n > 2048;
    float zzr = mir ? (ar + bi) : (ar - bi);
    float zzi = mir ? (br - ai) : (ai + br);
    zr[q] = dc ? ar : zzr;
    zi[q] = dc ? br : zzi;
  }
  // ---- stage 1: IDFT16 over k2 (no twiddle); write A[k0,k1,n0]
  idft16(zr, zi);
  {
    int base = (tid >> 4) + 17 * (tid & 15);   // k1 + 17*k0
#pragma unroll
    for (int m = 0; m < 16; ++m) { LR[base + 272 * m] = zr[m]; LI[base + 272 * m] = zi[m]; }
  }
  __syncthreads();
  // ---- stage 2: thread (k0=tid&15, n0=tid>>4); read A over k1 (contiguous)
  {
    int base = 17 * (tid & 15) + 272 * (tid >> 4);
#pragma unroll
    for (int q = 0; q < 16; ++q) { zr[q] = LR[base + q]; zi[q] = LI[base + q]; }
  }
  __syncthreads();
  twiddle_chain(zr, zi, (float)(tid >> 4) * TW256);   // cis(2pi n0 k1/256)
  idft16(zr, zi);
  {
    int base = (tid & 15) + 17 * (tid >> 4);   // k0 + 17*n0
#pragma unroll
    for (int m = 0; m < 16; ++m) { LR[base + 272 * m] = zr[m]; LI[base + 272 * m] = zi[m]; }
  }
  __syncthreads();
  // ---- stage 3: thread (n0=tid&15, n1=tid>>4); read B over k0 (contiguous)
  {
    int base = 17 * (tid & 15) + 272 * (tid >> 4);
#pragma unroll
    for (int q = 0; q < 16; ++q) { zr[q] = LR[base + q]; zi[q] = LI[base + q]; }
  }
  twiddle_chain(zr, zi, (float)tid * TW);      // cis(2pi (n0+16n1) k0/4096), n0+16n1 == tid
  idft16(zr, zi);
  // ---- windowed bf16 pack + store: sample n = 256*m + tid; a = Re, b = Im.
  // Pair packing via shfl with lane^1: even lanes store frame a dwords,
  // odd lanes store frame b dwords (win/256 folded into the store).
  unsigned int* da = (unsigned int*)(Fr + (size_t)ta * NFFT);
  unsigned int* db = (unsigned int*)(Fr + (size_t)(ta + 1) * NFFT);
  const bool even = (tid & 1) == 0;
#pragma unroll
  for (int m = 0; m < 16; ++m) {
    int n = 256 * m + tid;
    float w = (0.5f - 0.5f * __cosf((float)n * TW)) * 0.00390625f;   // win/256
    float va = zr[m] * w, vb = zi[m] * w;
    float xa = __shfl_xor(va, 1);
    float xb = __shfl_xor(vb, 1);
    unsigned int pa = ((unsigned int)f2b(xa) << 16) | f2b(va);  // even: (n, n+1)
    unsigned int pb = ((unsigned int)f2b(vb) << 16) | f2b(xb);  // odd:  (n-1, n)
    int dw = 128 * m + (tid >> 1);
    if (even)      da[dw] = pa;
    else if (hasb) db[dw] = pb;
  }
}

// ---------------------------------------------------------------------------
// Overlap-add gather, x8 vectorized: 8 consecutive samples per thread, all
// sharing the same 4-tap frame range (boundaries at multiples of 1024, s0
// multiple of 8). One ushort8 (dwordx4) load per tap, fixed-trip unrolled
// 4-tap loop with per-tap predication (interior: exactly 4 taps -> 4
// independent loads in flight). Interior window_sum == 1.5 exactly, so wsi
// is the constant W_INT except the first/last ~1.8k samples (same numeric
// coverage boundary as the round-2/3 verified version: samples < 3072 and
// > 353279 load wsi). 1D grid, b = bid&7 matches the ifft producer's XCD;
// ascending pblk reads the reversed-ifft's freshest Fr (low t) first.
__global__ __launch_bounds__(256) void ola(const unsigned short* __restrict__ Fr,
                                           const float* __restrict__ wsi,
                                           float* __restrict__ out, int length) {
  const int bid = blockIdx.x;
  const int b = bid & 7;                      // batch -> XCD
  const int pblk = bid >> 3;                  // 0..172
  int q = pblk * 256 + threadIdx.x;
  int p8 = q * 8;
  if (p8 >= length) return;
  int s0 = (NFFT / 2) + p8;                   // multiple of 8
  int t3 = s0 >> 10;                          // top tap frame (may be > T_FR-1)
  float a[8] = {0.f, 0.f, 0.f, 0.f, 0.f, 0.f, 0.f, 0.f};
#pragma unroll
  for (int d = 0; d < 4; ++d) {
    int t = t3 - 3 + d;
    if ((unsigned)t < (unsigned)T_FR) {
      const unsigned short* fp = Fr + ((size_t)(b * T_FR + t)) * NFFT + (s0 - (t << 10));
      const ushort4* fp4 = (const ushort4*)fp;    // 16B aligned: s0 % 8 == 0
      ushort4 v0 = fp4[0];
      ushort4 v1 = fp4[1];
      a[0] += b2f(v0.x); a[1] += b2f(v0.y); a[2] += b2f(v0.z); a[3] += b2f(v0.w);
      a[4] += b2f(v1.x); a[5] += b2f(v1.y); a[6] += b2f(v1.z); a[7] += b2f(v1.w);
    }
  }
  float4 w0, w1;
  if (s0 >= 3072 && s0 <= 353272) {           // interior: analytic wsi
    w0.x = w0.y = w0.z = w0.w = W_INT;
    w1 = w0;
  } else {
    w0 = *(const float4*)(wsi + s0);
    w1 = *(const float4*)(wsi + s0 + 4);
  }
  float* op = out + (size_t)b * length + p8;
  float4 o0, o1;
  o0.x = a[0] * w0.x; o0.y = a[1] * w0.y; o0.z = a[2] * w0.z; o0.w = a[3] * w0.w;
  o1.x = a[4] * w1.x; o1.y = a[5] * w1.y; o1.z = a[6] * w1.z; o1.w = a[7] * w1.w;
  *(float4*)(op)     = o0;
  *(float4*)(op + 4) = o1;
}

// ---------------------------------------------------------------------------
extern "C" void kernel_launch(void* const* d_in, const int* in_sizes, int n_in,
                              void* d_out, int out_size, void* d_ws, size_t ws_size,
                              hipStream_t stream) {
  const float* re  = (const float*)d_in[0];
  const float* im  = (const float*)d_in[1];
  // d_in[2] (inverse_basis) unused — spectral identity HW-verified previously.
  const float* wsi = (const float*)d_in[3];
  float* out = (float*)d_out;
  const int length = out_size / B_SZ;   // 352800

  // Workspace (45.2 MB): spec packed-bf16 [MFR x 2049], Fr bf16 [MFR x 4096].
  unsigned int*   spec = (unsigned int*)d_ws;
  unsigned short* Fr   = (unsigned short*)(spec + (size_t)MFR * C_IN);

  // All grids are multiples of 8; b = bid&7 keeps each batch on one XCD
  // across the whole producer->consumer chain (spec and Fr L2 residency).
  trans<<<dim3(8 * 198), 256, 0, stream>>>(re, im, spec);        // 198 tiles/batch
  ifft_frames<<<dim3(8 * NPAIR), 256, 0, stream>>>(spec, Fr);    // 173 pairs/batch
  ola<<<dim3(8 * 173), 256, 0, stream>>>(Fr, wsi, out, length);  // 173 blocks/batch
}